// Round 2
// baseline (1660.411 us; speedup 1.0000x reference)
//
#include <hip/hip_runtime.h>
#include <cstdint>

// B=4, S=2048, d=2048, dff=8192. Inputs fp32, output fp32.
// All GEMMs bf16 MFMA (fp32 accum). Weights pre-converted fp32->bf16 per phase.
//
// ws (112 MiB): w0[0,32) x1 -> h2 | w1[32,64) Vt -> f1
//               w2[64,96) Wqkv_bf(24) -> attn(32) | w3[96,112) scP(8,bf16) -> Wo_bf(8) -> W1c(8)+W2c(8)
// d_out (64 MiB fp32): Q bf16 [0,32MiB) + K bf16 [32,64MiB) until PROJ, then src2 fp32 (in-place final).
//
// Big GEMMs (QKV/PROJ/FFN1/F2A): gemm256 = 256x256 tile, BK=64, 8 waves (2Mx4N),
// 4-phase-per-K-tile pipelined schedule: every phase issues exactly 6 ds_read_b128
// for the NEXT phase's operands + 1 half-tile stage, waits lgkmcnt(6) (counted:
// previous phase's reads done, own 6 in flight), 16 MFMA, single barrier.
// LDS reads overlap MFMA; vmcnt(2) gates (pre-barrier) keep stages 2 phases deep.

typedef __attribute__((ext_vector_type(8))) short short8;
typedef __attribute__((ext_vector_type(4))) float floatx4;

#define PLANE 16777216L   // 8192*2048 (Q->K plane stride, elements)
#define SS    4194304L    // 2048*2048 (per-batch matrix, elements)

__device__ __forceinline__ float bf2f(unsigned short u) {
    union { unsigned int i; float f; } v; v.i = ((unsigned int)u) << 16; return v.f;
}
__device__ __forceinline__ unsigned short f2bf(float f) {
    union { float f; unsigned int i; } v; v.f = f;
    unsigned int x = v.i;
    return (unsigned short)((x + 0x7FFFu + ((x >> 16) & 1u)) >> 16);
}
__device__ __forceinline__ uint4 pack8(float4 a, float4 b) {
    unsigned short o[8];
    o[0] = f2bf(a.x); o[1] = f2bf(a.y); o[2] = f2bf(a.z); o[3] = f2bf(a.w);
    o[4] = f2bf(b.x); o[5] = f2bf(b.y); o[6] = f2bf(b.z); o[7] = f2bf(b.w);
    return *(uint4*)o;
}
// async global->LDS, 16B per lane; LDS dest = wave-uniform base + lane*16
__device__ __forceinline__ void gl_lds16(const void* g, void* l) {
    __builtin_amdgcn_global_load_lds(
        (const __attribute__((address_space(1))) void*)g,
        (__attribute__((address_space(3))) void*)l, 16, 0, 0);
}

#define EM_QKV  0
#define EM_SC   1
#define EM_PV   2
#define EM_PROJ 3
#define EM_FFN1 4
#define EM_F2A  5

// ---------------------------------------------------------------------------
// Legacy 128x128 kernel — kept for the causal attention GEMMs (SC, PV).
// ---------------------------------------------------------------------------
template<int EM>
__launch_bounds__(256, 2)
__global__ void gemm_bt(const unsigned short* __restrict__ A,
                        const unsigned short* __restrict__ B,
                        void* __restrict__ Cv, int N, int K,
                        const float* __restrict__ bias,
                        const unsigned short* __restrict__ resid16,
                        unsigned short* __restrict__ outQ,
                        unsigned short* __restrict__ outVt)
{
    constexpr int BM = 128, BN = 128, BK = 32;
    __shared__ __align__(16) unsigned short As[BM * BK];
    __shared__ __align__(16) unsigned short Bs[BN * BK];

    const int m0 = blockIdx.x * BM, n0 = blockIdx.y * BN;
    if (EM == EM_SC && n0 > m0 + (BM - 1)) return;   // fully-masked causal tile

    int kmax = K;
    if (EM == EM_PV) { kmax = m0 + BM; if (kmax > K) kmax = K; }  // P zero past causal edge
    const int nsteps = kmax / BK;

    const int t = threadIdx.x;
    const int lane = t & 63, wave = t >> 6;
    const int q = lane >> 4, ln = lane & 15;
    const int wm = (wave >> 1) * 64, wn = (wave & 1) * 64;

    const int r0 = wave * 32;
    const int rA = r0 + (lane >> 2);
    const int cslot = lane & 3;
    const int cg0 = (cslot ^ (rA & 3)) * 8;
    const int cg1 = (cslot ^ ((rA + 16) & 3)) * 8;
    const unsigned short* Agp0 = A + (long)(m0 + rA) * K + cg0;
    const unsigned short* Agp1 = A + (long)(m0 + rA + 16) * K + cg1;
    const unsigned short* Bgp0 = B + (long)(n0 + rA) * K + cg0;
    const unsigned short* Bgp1 = B + (long)(n0 + rA + 16) * K + cg1;
    unsigned short* lA0 = &As[r0 * 32];
    unsigned short* lA1 = &As[(r0 + 16) * 32];
    unsigned short* lB0 = &Bs[r0 * 32];
    unsigned short* lB1 = &Bs[(r0 + 16) * 32];

    floatx4 acc[4][4];
#pragma unroll
    for (int i = 0; i < 4; ++i)
#pragma unroll
        for (int j = 0; j < 4; ++j) acc[i][j] = (floatx4){0.f, 0.f, 0.f, 0.f};

    for (int s = 0; s < nsteps; ++s) {
        const long off = (long)s * BK;
        __syncthreads();
        gl_lds16(Agp0 + off, lA0);
        gl_lds16(Agp1 + off, lA1);
        gl_lds16(Bgp0 + off, lB0);
        gl_lds16(Bgp1 + off, lB1);
        __syncthreads();
        short8 af[4], bfr[4];
#pragma unroll
        for (int i = 0; i < 4; ++i) {
            const int R = wm + 16 * i + ln;
            af[i] = *(const short8*)&As[R * 32 + ((q ^ (R & 3)) * 8)];
        }
#pragma unroll
        for (int j = 0; j < 4; ++j) {
            const int R = wn + 16 * j + ln;
            bfr[j] = *(const short8*)&Bs[R * 32 + ((q ^ (R & 3)) * 8)];
        }
#pragma unroll
        for (int i = 0; i < 4; ++i)
#pragma unroll
            for (int j = 0; j < 4; ++j)
                acc[i][j] = __builtin_amdgcn_mfma_f32_16x16x32_bf16(af[i], bfr[j], acc[i][j], 0, 0, 0);
    }

#pragma unroll
    for (int i = 0; i < 4; ++i) {
#pragma unroll
        for (int r = 0; r < 4; ++r) {
            const int row = m0 + wm + 16 * i + q * 4 + r;
#pragma unroll
            for (int j = 0; j < 4; ++j) {
                const int col = n0 + wn + 16 * j + ln;
                float v = acc[i][j][r];
                const long idx = (long)row * N + col;
                if constexpr (EM == EM_SC) {
                    ((unsigned short*)Cv)[idx] = f2bf(v);
                } else if constexpr (EM == EM_PV) {
                    ((unsigned short*)Cv)[idx] = f2bf(v);
                }
            }
        }
    }
}

// ---------------------------------------------------------------------------
// gemm256: 256x256 / BK=64 / 8-wave, pipelined 4-phase groups.
//
// Group g computes K-tile g from buf (g&1). Quadrants: P1=Q00(a0,b0),
// P2=Q01(a0,b1), P3=Q10(a1,b0), P4=Q11(a1,b1). Read-ahead by exactly one
// phase (6 ds_read_b128/phase):
//   P1: b1(g)+a1(g)[0]   P2: a1(g)[1..3]   P3: a0(g+1)[0..2]   P4: a0(g+1)[3]+b0(g+1)
// (a0/b0 of tile 0 are pre-read in the prologue.)
// Stages (1 half-tile = 2 gl_lds16 per phase):
//   P1: A(g+1)h1 -> nxt   P2: B(g+1)h1 -> nxt   P3: B(g+2)h0 -> cur   P4: A(g+2)h0 -> cur
// Deadness (single barrier per phase; lgkmcnt(6) at phase p globally completes
// all reads issued <= p-1 by the barrier of p):
//   A(g-1)h1 dead at BAR(g-1.3) -> P1 stage ok;  B(g-1)h1 dead at BAR(g-1.2) -> P2 ok
//   B(g)h0  dead at BAR(g.2)   -> P3 stage ok;  A(g)h0  dead at BAR(g.3)   -> P4 ok
// Gates (per-wave vmcnt + the phase barrier globalizes):
//   end P2: vmcnt(2) -> A(g+1) complete (h0 @ (g-1).4, h1 @ g.1) before P3 reads
//   end P3: vmcnt(2) -> B(g+1) complete (h0 @ (g-1).3, h1 @ g.2) before P4 reads
// LDS swizzle: 16B chunk c of row r stored at c^(r&7); global source pre-swizzled
// (global_load_lds writes linearly), ds_read applies the same XOR. 0 conflicts (R1).
// ---------------------------------------------------------------------------
#define BARM()   do { __builtin_amdgcn_s_barrier(); asm volatile("" ::: "memory"); } while (0)
#define LGKM(n)  asm volatile("s_waitcnt lgkmcnt(" #n ")" ::: "memory")
#define VMCNT(n) asm volatile("s_waitcnt vmcnt(" #n ")" ::: "memory")
#define PRIO1()  __builtin_amdgcn_s_setprio(1)
#define PRIO0()  __builtin_amdgcn_s_setprio(0)

template<int EM>
__launch_bounds__(512, 2)
__global__ void gemm256(const unsigned short* __restrict__ A,
                        const unsigned short* __restrict__ B,
                        void* __restrict__ Cv, int N, int K,
                        const float* __restrict__ bias,
                        const unsigned short* __restrict__ resid16,
                        unsigned short* __restrict__ outQ,
                        unsigned short* __restrict__ outVt)
{
    __shared__ __align__(16) unsigned short As[2][16384];
    __shared__ __align__(16) unsigned short Bs[2][16384];

    const int m0 = blockIdx.x * 256, n0 = blockIdx.y * 256;
    const int t = threadIdx.x;
    const int lane = t & 63, wave = t >> 6;
    const int q = lane >> 4, ln = lane & 15;
    const int wm = wave >> 2, wn = wave & 3;      // 2 x 4 wave grid, 128x64 out each

    // staging geometry: per half-tile (128 rows x 64 cols) each wave covers
    // rows [wave*16, wave*16+16) via 2 insts of 8 rows; global chunk pre-swizzled.
    const int jrow = lane >> 3;
    const int csrc = ((lane & 7) ^ jrow) * 8;
    const unsigned short* Ag = A + (long)(m0 + wave * 16 + jrow) * K + csrc;
    const unsigned short* Bg = B + (long)(n0 + wave * 16 + jrow) * K + csrc;
    const int ldsSlice = wave * 1024;             // elements; +512 for inst 1

    // ds_read geometry (swizzled chunk = (kk*4+q) ^ (ln&7))
    const int aBase = (wm * 128 + ln) * 64;
    const int bBase = (wn * 64 + ln) * 64;
    const int c0 = ((0 + q) ^ (ln & 7)) * 8;
    const int c1 = ((4 + q) ^ (ln & 7)) * 8;

    floatx4 acc[8][4];
#pragma unroll
    for (int i = 0; i < 8; ++i)
#pragma unroll
        for (int j = 0; j < 4; ++j) acc[i][j] = (floatx4){0.f, 0.f, 0.f, 0.f};

    short8 a0r[4][2], a1r[4][2];   // mg0 / mg1 fragment sets (both live)
    short8 b0r[2][2], b1r[2][2];   // ng0 / ng1 fragment sets

#define STAGE_A(buf, kt, h) do { \
    const unsigned short* _g = Ag + (long)((h) * 128) * K + ((long)(kt) << 6); \
    gl_lds16(_g,          &As[buf][(h) * 8192 + ldsSlice]); \
    gl_lds16(_g + 8L * K, &As[buf][(h) * 8192 + ldsSlice + 512]); \
} while (0)
#define STAGE_B(buf, kt, h) do { \
    const unsigned short* _g = Bg + (long)((h) * 128) * K + ((long)(kt) << 6); \
    gl_lds16(_g,          &Bs[buf][(h) * 8192 + ldsSlice]); \
    gl_lds16(_g + 8L * K, &Bs[buf][(h) * 8192 + ldsSlice + 512]); \
} while (0)
// one A fragment (2 reads): rows wm*128 + mg*64 + 16*i + ln
#define RD_A0F(sel, i) { \
    a0r[i][0] = *(const short8*)&As[sel][aBase + (16 * (i)) * 64 + c0]; \
    a0r[i][1] = *(const short8*)&As[sel][aBase + (16 * (i)) * 64 + c1]; }
#define RD_A1F(sel, i) { \
    a1r[i][0] = *(const short8*)&As[sel][aBase + (64 + 16 * (i)) * 64 + c0]; \
    a1r[i][1] = *(const short8*)&As[sel][aBase + (64 + 16 * (i)) * 64 + c1]; }
// full B half-set (4 reads): rows wn*64 + ng*32 + 16*j + ln
#define RD_B0A(sel) { \
    _Pragma("unroll") \
    for (int j = 0; j < 2; ++j) { \
        b0r[j][0] = *(const short8*)&Bs[sel][bBase + (16 * j) * 64 + c0]; \
        b0r[j][1] = *(const short8*)&Bs[sel][bBase + (16 * j) * 64 + c1]; } }
#define RD_B1A(sel) { \
    _Pragma("unroll") \
    for (int j = 0; j < 2; ++j) { \
        b1r[j][0] = *(const short8*)&Bs[sel][bBase + (32 + 16 * j) * 64 + c0]; \
        b1r[j][1] = *(const short8*)&Bs[sel][bBase + (32 + 16 * j) * 64 + c1]; } }
#define MMQ(ar, br, mg, ng) { \
    _Pragma("unroll") \
    for (int i = 0; i < 4; ++i) \
    _Pragma("unroll") \
    for (int j = 0; j < 2; ++j) { \
        acc[(mg)*4+i][(ng)*2+j] = __builtin_amdgcn_mfma_f32_16x16x32_bf16( \
            ar[i][0], br[j][0], acc[(mg)*4+i][(ng)*2+j], 0, 0, 0); \
        acc[(mg)*4+i][(ng)*2+j] = __builtin_amdgcn_mfma_f32_16x16x32_bf16( \
            ar[i][1], br[j][1], acc[(mg)*4+i][(ng)*2+j], 0, 0, 0); \
    } }

    const int NG = K >> 6;   // K-tiles of 64 cols; NG even, >= 4

    // prologue: tile0 (8 loads), then tile1 h0 parts in steady-state order
    // (B(1)h0 = "(g-1).3", A(1)h0 = "(g-1).4"); gate tile0 with vmcnt(4).
    STAGE_A(0, 0, 0); STAGE_A(0, 0, 1);
    STAGE_B(0, 0, 0); STAGE_B(0, 0, 1);
    STAGE_B(1, 1, 0);
    STAGE_A(1, 1, 0);
    VMCNT(4); BARM();
    // pre-reads (the "(g-1).3/.4" reads for group 0): a0(0) + b0(0) = 12 reads
    RD_A0F(0, 0); RD_A0F(0, 1); RD_A0F(0, 2); RD_A0F(0, 3);
    RD_B0A(0);

    for (int g = 0; g < NG - 2; ++g) {
        const int cur = g & 1, nxt = cur ^ 1;
        // P1: Q00
        RD_B1A(cur); RD_A1F(cur, 0);
        STAGE_A(nxt, g + 1, 1);
        LGKM(6);
        PRIO1(); MMQ(a0r, b0r, 0, 0); PRIO0();
        BARM();
        // P2: Q01  (+ gate A(g+1))
        RD_A1F(cur, 1); RD_A1F(cur, 2); RD_A1F(cur, 3);
        STAGE_B(nxt, g + 1, 1);
        LGKM(6);
        PRIO1(); MMQ(a0r, b1r, 0, 1); PRIO0();
        VMCNT(2); BARM();
        // P3: Q10  (+ gate B(g+1))
        RD_A0F(nxt, 0); RD_A0F(nxt, 1); RD_A0F(nxt, 2);
        STAGE_B(cur, g + 2, 0);
        LGKM(6);
        PRIO1(); MMQ(a1r, b0r, 1, 0); PRIO0();
        VMCNT(2); BARM();
        // P4: Q11
        RD_A0F(nxt, 3); RD_B0A(nxt);
        STAGE_A(cur, g + 2, 0);
        LGKM(6);
        PRIO1(); MMQ(a1r, b1r, 1, 1); PRIO0();
        BARM();
    }
    // peel g = NG-2: stages for tile NG suppressed (P3/P4); gates adjusted
    {
        const int g = NG - 2, cur = g & 1, nxt = cur ^ 1;
        RD_B1A(cur); RD_A1F(cur, 0);
        STAGE_A(nxt, g + 1, 1);
        LGKM(6);
        PRIO1(); MMQ(a0r, b0r, 0, 0); PRIO0();
        BARM();
        RD_A1F(cur, 1); RD_A1F(cur, 2); RD_A1F(cur, 3);
        STAGE_B(nxt, g + 1, 1);
        LGKM(6);
        PRIO1(); MMQ(a0r, b1r, 0, 1); PRIO0();
        VMCNT(2); BARM();
        RD_A0F(nxt, 0); RD_A0F(nxt, 1); RD_A0F(nxt, 2);
        LGKM(6);
        PRIO1(); MMQ(a1r, b0r, 1, 0); PRIO0();
        VMCNT(0); BARM();
        RD_A0F(nxt, 3); RD_B0A(nxt);
        LGKM(6);
        PRIO1(); MMQ(a1r, b1r, 1, 1); PRIO0();
        BARM();
    }
    // peel g = NG-1: no stages, no gates, no barriers needed
    {
        const int cur = (NG - 1) & 1;
        RD_B1A(cur); RD_A1F(cur, 0);
        LGKM(6);
        PRIO1(); MMQ(a0r, b0r, 0, 0); PRIO0();
        RD_A1F(cur, 1); RD_A1F(cur, 2); RD_A1F(cur, 3);
        LGKM(6);
        PRIO1(); MMQ(a0r, b1r, 0, 1); PRIO0();
        LGKM(0);
        PRIO1(); MMQ(a1r, b0r, 1, 0); PRIO0();
        PRIO1(); MMQ(a1r, b1r, 1, 1); PRIO0();
    }

#undef STAGE_A
#undef STAGE_B
#undef RD_A0F
#undef RD_A1F
#undef RD_B0A
#undef RD_B1A
#undef MMQ

    // epilogue: within 16x16 tile, row = q*4+reg, col = ln (verified m89/m91)
#pragma unroll
    for (int i = 0; i < 8; ++i) {
#pragma unroll
        for (int r = 0; r < 4; ++r) {
            const int row = m0 + wm * 128 + 16 * i + q * 4 + r;
#pragma unroll
            for (int j = 0; j < 4; ++j) {
                const int col = n0 + wn * 64 + 16 * j + ln;
                float v = acc[i][j][r];
                const long idx = (long)row * N + col;
                if constexpr (EM == EM_QKV) {
                    v += bias[col];
                    const unsigned short vb = f2bf(v);
                    const int p = col >> 11, c2 = col & 2047;
                    if (p == 0)      outQ[(long)row * 2048 + c2] = vb;
                    else if (p == 1) (outQ + PLANE)[(long)row * 2048 + c2] = vb;
                    else             outVt[(long)(row >> 11) * SS + (long)c2 * 2048 + (row & 2047)] = vb;
                } else if constexpr (EM == EM_PROJ) {
                    v += bias[col] + bf2f(resid16[idx]);    // resid = LN1 out (bf16 x1)
                    ((float*)Cv)[idx] = v;
                } else if constexpr (EM == EM_FFN1) {
                    v = fmaxf(v + bias[col], 0.f);
                    ((unsigned short*)Cv)[idx] = f2bf(v);
                } else { // EM_F2A
                    ((float*)Cv)[idx] += v;
                }
            }
        }
    }
}

// rows of length 2048: fp32 (stride srcld) -> bf16 (stride 2048)
__launch_bounds__(256)
__global__ void cvt_rows(const float* __restrict__ src, unsigned short* __restrict__ dst, long srcld)
{
    const int row = blockIdx.x, t = threadIdx.x;
    const float* s = src + (long)row * srcld + t * 8;
    float4 a = *(const float4*)s;
    float4 b = *(const float4*)(s + 4);
    *(uint4*)(dst + (long)row * 2048 + t * 8) = pack8(a, b);
}

// LayerNorm: fp32 in (2048 cols), bf16 out; fp32 gamma/beta.
__launch_bounds__(256)
__global__ void layernorm_k(const float* __restrict__ X, unsigned short* __restrict__ Y,
                            const float* __restrict__ g, const float* __restrict__ be)
{
    const int row = blockIdx.x, t = threadIdx.x;
    const float* Xr = X + (long)row * 2048 + t * 8;
    float4 v0 = *(const float4*)Xr;
    float4 v1 = *(const float4*)(Xr + 4);
    float x[8] = {v0.x, v0.y, v0.z, v0.w, v1.x, v1.y, v1.z, v1.w};
    float s = 0.f, ss = 0.f;
#pragma unroll
    for (int k = 0; k < 8; ++k) { s += x[k]; ss += x[k] * x[k]; }
    for (int off = 32; off; off >>= 1) { s += __shfl_down(s, off, 64); ss += __shfl_down(ss, off, 64); }
    __shared__ float red[8];
    const int wave = t >> 6, lane = t & 63;
    if (lane == 0) { red[wave] = s; red[4 + wave] = ss; }
    __syncthreads();
    s  = red[0] + red[1] + red[2] + red[3];
    ss = red[4] + red[5] + red[6] + red[7];
    const float mean = s * (1.f / 2048.f);
    const float var  = ss * (1.f / 2048.f) - mean * mean;
    const float rstd = rsqrtf(var + 1e-5f);
    unsigned short o[8];
#pragma unroll
    for (int k = 0; k < 8; ++k) {
        const int col = t * 8 + k;
        o[k] = f2bf((x[k] - mean) * rstd * g[col] + be[col]);
    }
    *(uint4*)(Y + (long)row * 2048 + t * 8) = *(uint4*)o;
}

// In-place RoPE on bf16 Q (blockIdx.y=0) / K (=1), replicating the reference quirk:
// emb = concat(sin(sp),cos(sp)); c=cos(emb), s=sin(emb); rh = concat(-x[::2], x[1::2]).
__launch_bounds__(256)
__global__ void rope_inplace(unsigned short* __restrict__ Q, unsigned short* __restrict__ K)
{
    __shared__ __align__(16) unsigned short rowbuf[2048];
    const int row = blockIdx.x;              // 0..8191 (b*2048+p)
    const int mtx = blockIdx.y;
    unsigned short* X = (mtx ? K : Q) + (long)row * 2048;
    const int t = threadIdx.x;
    *(uint4*)&rowbuf[t * 8] = *(const uint4*)(X + t * 8);
    __syncthreads();
    const int p = row & 2047;
    const float sgn = mtx ? -1.f : 1.f;
    unsigned short o[8];
#pragma unroll
    for (int e = 0; e < 8; ++e) {
        const int j = t * 8 + e;
        const int i = j & 1023;
        const float freq = __expf(-(float)i * (9.210340371976184f / 1024.0f)); // 10000^(-i/1024)
        const float sp = (float)p * freq;
        const float emb = (j < 1024) ? sinf(sp) : cosf(sp);
        float se, ce;
        sincosf(emb, &se, &ce);
        const int pj = (j < 1024) ? (2 * j) : (2 * j - 2047);
        float xp = bf2f(rowbuf[pj]);
        if (j < 1024) xp = -xp;
        o[e] = f2bf(bf2f(rowbuf[j]) * ce + sgn * xp * se);
    }
    *(uint4*)(X + t * 8) = *(uint4*)o;
}

// Causal softmax in-place on bf16 scores (2048x2048); full rows written (zeros past edge).
__launch_bounds__(256)
__global__ void softmax_causal(unsigned short* __restrict__ S)
{
    const int qq = blockIdx.x;
    const int L = qq + 1;
    unsigned short* srow = S + (long)qq * 2048;
    const int t = threadIdx.x;
    const float scale = 0.022097086912079608f; // 1/sqrt(2048)
    float vals[8];
    float m = -1e30f;
#pragma unroll
    for (int u = 0; u < 8; ++u) {
        const int i2 = t + 256 * u;
        vals[u] = (i2 < L) ? bf2f(srow[i2]) * scale : -1e30f;
        m = fmaxf(m, vals[u]);
    }
    for (int off = 32; off; off >>= 1) m = fmaxf(m, __shfl_down(m, off, 64));
    __shared__ float red[8];
    const int wave = t >> 6, lane = t & 63;
    if (lane == 0) red[wave] = m;
    __syncthreads();
    m = fmaxf(fmaxf(red[0], red[1]), fmaxf(red[2], red[3]));
    float sum = 0.f;
#pragma unroll
    for (int u = 0; u < 8; ++u) {
        float e = __expf(vals[u] - m);
        e = (t + 256 * u < L) ? e : 0.f;
        vals[u] = e; sum += e;
    }
    for (int off = 32; off; off >>= 1) sum += __shfl_down(sum, off, 64);
    if (lane == 0) red[4 + wave] = sum;
    __syncthreads();
    sum = red[4] + red[5] + red[6] + red[7];
    const float inv = 1.0f / sum;
#pragma unroll
    for (int u = 0; u < 8; ++u) srow[t + 256 * u] = f2bf(vals[u] * inv);
}

// io += b2 (in place on d_out; src2 already holds residual + FFN2 accumulation)
__launch_bounds__(256)
__global__ void final_add(float* __restrict__ io, const float* __restrict__ b2)
{
    const int row = blockIdx.x, t = threadIdx.x;
    const long base = (long)row * 2048 + t * 8;
    float4 a0 = *(const float4*)(io + base);
    float4 a1 = *(const float4*)(io + base + 4);
    float4 c0 = *(const float4*)(b2 + t * 8);
    float4 c1 = *(const float4*)(b2 + t * 8 + 4);
    a0.x += c0.x; a0.y += c0.y; a0.z += c0.z; a0.w += c0.w;
    a1.x += c1.x; a1.y += c1.y; a1.z += c1.z; a1.w += c1.w;
    *(float4*)(io + base) = a0;
    *(float4*)(io + base + 4) = a1;
}

extern "C" void kernel_launch(void* const* d_in, const int* in_sizes, int n_in,
                              void* d_out, int out_size, void* d_ws, size_t ws_size,
                              hipStream_t stream)
{
    const float* src  = (const float*)d_in[0];
    const float* Wqkv = (const float*)d_in[1];
    const float* bqkv = (const float*)d_in[2];
    const float* Wo   = (const float*)d_in[3];
    const float* bo   = (const float*)d_in[4];
    const float* W1   = (const float*)d_in[5];
    const float* b1   = (const float*)d_in[6];
    const float* W2   = (const float*)d_in[7];
    const float* b2   = (const float*)d_in[8];
    const float* g1   = (const float*)d_in[9];
    const float* be1  = (const float*)d_in[10];
    const float* g2   = (const float*)d_in[11];
    const float* be2  = (const float*)d_in[12];

    char* ws = (char*)d_ws;
    const long MB = 1LL << 20;
    unsigned short* x1    = (unsigned short*)ws;                 // w0: LN1 out -> h2
    unsigned short* Vt    = (unsigned short*)(ws + 32 * MB);     // w1: Vt -> f1
    unsigned short* Wqbf  = (unsigned short*)(ws + 64 * MB);     // w2: Wqkv_bf -> attn
    unsigned short* attn  = (unsigned short*)(ws + 64 * MB);
    unsigned short* scP   = (unsigned short*)(ws + 96 * MB);     // w3: bf16 scores/P (8 MiB)
    unsigned short* Wobf  = (unsigned short*)(ws + 96 * MB);     //     -> Wo_bf (8 MiB)
    unsigned short* W1c   = (unsigned short*)(ws + 96 * MB);     //     -> W1 chunk (8 MiB)
    unsigned short* W2c   = (unsigned short*)(ws + 104 * MB);    //     -> W2 chunk (8 MiB)
    unsigned short* h2    = x1;
    unsigned short* f1    = Vt;

    unsigned short* Q    = (unsigned short*)d_out;               // Q [0,32MiB), K [32,64MiB)
    float*          src2 = (float*)d_out;                        // after PROJ (Q,K dead)
    float*          out  = (float*)d_out;

    const dim3 blk(256);
    const dim3 blk512(512);

    cvt_rows<<<6144, blk, 0, stream>>>(Wqkv, Wqbf, 2048);
    layernorm_k<<<8192, blk, 0, stream>>>(src, x1, g1, be1);
    gemm256<EM_QKV><<<dim3(32, 24), blk512, 0, stream>>>(
        x1, Wqbf, nullptr, 6144, 2048, bqkv, nullptr, Q, Vt);
    rope_inplace<<<dim3(8192, 2), blk, 0, stream>>>(Q, Q + PLANE);

    for (int b = 0; b < 4; ++b) {
        gemm_bt<EM_SC><<<dim3(16, 16), blk, 0, stream>>>(
            Q + b * SS, Q + PLANE + b * SS, scP, 2048, 2048, nullptr, nullptr, nullptr, nullptr);
        softmax_causal<<<2048, blk, 0, stream>>>(scP);
        gemm_bt<EM_PV><<<dim3(16, 16), blk, 0, stream>>>(
            scP, Vt + b * SS, attn + b * SS, 2048, 2048, nullptr, nullptr, nullptr, nullptr);
    }

    cvt_rows<<<2048, blk, 0, stream>>>(Wo, Wobf, 2048);
    gemm256<EM_PROJ><<<dim3(32, 8), blk512, 0, stream>>>(
        attn, Wobf, src2, 2048, 2048, bo, x1, nullptr, nullptr);
    layernorm_k<<<8192, blk, 0, stream>>>(src2, h2, g2, be2);

    for (int c = 0; c < 4; ++c) {
        cvt_rows<<<2048, blk, 0, stream>>>(W1 + (long)c * 2048 * 2048, W1c, 2048);
        cvt_rows<<<2048, blk, 0, stream>>>(W2 + (long)c * 2048, W2c, 8192);
        gemm256<EM_FFN1><<<dim3(32, 8), blk512, 0, stream>>>(
            h2, W1c, f1, 2048, 2048, b1 + c * 2048, nullptr, nullptr, nullptr);
        gemm256<EM_F2A><<<dim3(32, 8), blk512, 0, stream>>>(
            f1, W2c, src2, 2048, 2048, nullptr, nullptr, nullptr, nullptr);
    }
    final_add<<<8192, blk, 0, stream>>>(out, b2);
}